// Round 6
// baseline (961.547 us; speedup 1.0000x reference)
//
#include <hip/hip_runtime.h>

// out[n,k,y,x] = sum_c grid[n,k,c,y/16,x/16] * guidemap[n,c,y,x]
// N=2, K=C=32, H=W=1024, 64x64 tiles of 16x16 px.
//
// R6: full-row streaming decomposition.
//  - WG = 256 thr = (n, by, kq): 16 full image rows (1024 px) x 4 k, all c.
//  - Every guide load / out store: 64 lanes x float4 = 1 KB contiguous,
//    sweeping sequential 4KB rows (vs. R1-R5's 64B tile-scatter).
//  - Matrix slices (64 tiles x 32 c x 4 k = 32 KB) staged once to LDS
//    [c][bx][dk]; compute reads are conflict-free ds_read_b128.
//  - Guide sharing: bid = kq*128 + slab -> all 8 kq-WGs of a slab land on
//    XCD slab%8 (round-robin dispatch), all 1024 WGs co-resident -> each
//    guide line HBM-fetched once, re-served from that XCD's L2.

namespace {
constexpr int K = 32, C = 32;
constexpr int W = 1024, H = 1024;
constexpr int HW = H * W;
constexpr size_t GRDN = (size_t)K * C * 64 * 64;  // floats per image
}

__global__ __launch_bounds__(256, 4) void gridup_kernel(
    const float* __restrict__ grd,   // [N][K][C][64][64]
    const float* __restrict__ gm,    // [N][C][1024][1024]
    float* __restrict__ out)         // [N][K][1024][1024]
{
    __shared__ float sM[C][64][4];   // [c][bx][dk], 32 KB

    const int bid  = blockIdx.x;     // 0..1023
    const int kq   = bid >> 7;       // 0..7  (k-quad)
    const int slab = bid & 127;      // n*64 + by ; slab%8 selects XCD
    const int n    = slab >> 6;
    const int by   = slab & 63;
    const int k0   = kq * 4;
    const int t    = threadIdx.x;    // 0..255

    // ---- stage matrix slice: 8192 dwords, 256B-coalesced global reads
    {
        const float* gb = grd + (size_t)n * GRDN + (size_t)by * 64;
        #pragma unroll
        for (int i = 0; i < 32; ++i) {
            const int e  = i * 256 + t;   // 0..8191
            const int bx = e & 63;
            const int c  = (e >> 6) & 31;
            const int dk = e >> 11;
            sM[c][bx][dk] = gb[(size_t)((k0 + dk) * 32 + c) * 4096 + bx];
        }
    }
    __syncthreads();   // only barrier in the kernel

    const int bx = t >> 2;           // this thread's tile (4 px in one tile)
    const int x4 = t * 4;            // px column 0..1020
    const float* gmn = gm + (size_t)n * C * HW + x4;
    float*       on  = out + ((size_t)n * K + k0) * HW + x4;
    const int y0 = by * 16;

    #pragma unroll 1
    for (int rc = 0; rc < 8; ++rc) {     // row chunks: 2 rows each
        const size_t roff = (size_t)(y0 + rc * 2) * W;
        const float* gp = gmn + roff;

        float acc[2][4][4] = {};

        // ring-4 guide prefetch: g[j][r] holds channel (c: c&3==j), row r
        float4 g[4][2];
        #pragma unroll
        for (int j = 0; j < 4; ++j) {
            g[j][0] = *reinterpret_cast<const float4*>(gp + (size_t)j * HW);
            g[j][1] = *reinterpret_cast<const float4*>(gp + (size_t)j * HW + W);
        }

        #pragma unroll
        for (int c = 0; c < C; ++c) {
            const float4 m  = *reinterpret_cast<const float4*>(&sM[c][bx][0]);
            const float4 u0 = g[c & 3][0];
            const float4 u1 = g[c & 3][1];
            if (c + 4 < C) {
                g[c & 3][0] = *reinterpret_cast<const float4*>(
                    gp + (size_t)(c + 4) * HW);
                g[c & 3][1] = *reinterpret_cast<const float4*>(
                    gp + (size_t)(c + 4) * HW + W);
            }
            const float mv[4] = {m.x, m.y, m.z, m.w};
            #pragma unroll
            for (int dk = 0; dk < 4; ++dk) {
                acc[0][dk][0] += mv[dk] * u0.x;
                acc[0][dk][1] += mv[dk] * u0.y;
                acc[0][dk][2] += mv[dk] * u0.z;
                acc[0][dk][3] += mv[dk] * u0.w;
                acc[1][dk][0] += mv[dk] * u1.x;
                acc[1][dk][1] += mv[dk] * u1.y;
                acc[1][dk][2] += mv[dk] * u1.z;
                acc[1][dk][3] += mv[dk] * u1.w;
            }
        }

        // ---- stores: 8 x (64 lanes x float4 = 1 KB contiguous)
        #pragma unroll
        for (int dk = 0; dk < 4; ++dk) {
            float* op = on + (size_t)dk * HW + roff;
            *reinterpret_cast<float4*>(op) =
                make_float4(acc[0][dk][0], acc[0][dk][1], acc[0][dk][2], acc[0][dk][3]);
            *reinterpret_cast<float4*>(op + W) =
                make_float4(acc[1][dk][0], acc[1][dk][1], acc[1][dk][2], acc[1][dk][3]);
        }
    }
}

extern "C" void kernel_launch(void* const* d_in, const int* in_sizes, int n_in,
                              void* d_out, int out_size, void* d_ws, size_t ws_size,
                              hipStream_t stream) {
    const float* grd = (const float*)d_in[0];   // grid:     2*32*32*64*64
    const float* gm  = (const float*)d_in[1];   // guidemap: 2*32*1024*1024
    float* out = (float*)d_out;                 // 2*32*1024*1024 fp32

    gridup_kernel<<<1024, 256, 0, stream>>>(grd, gm, out);
}

// Round 8
// 274.201 us; speedup vs baseline: 3.5067x; 3.5067x over previous
//
#include <hip/hip_runtime.h>

// out[n,k,y,x] = sum_c grid[n,k,c,y/16,x/16] * guidemap[n,c,y,x]
// N=2, K=C=32, H=W=1024, 64x64 tiles of 16x16 px.
//
// R7b = R3 with halved per-byte instruction overhead (compile-fixed).
//  - Thread = 4 px x 32 k (acc[32] float4). LDS-broadcast reads, guide
//    loads, and stores all halve in instruction count vs R3 (same bytes).
//  - WG = 256 thr = 4 adjacent-bx tiles; wave = exactly one tile, so the
//    matrix ds_read_b128 stays wave-uniform (free broadcast, 0 conflicts).
//  - Matrices (4 tiles x 4 KB) staged once via global_load_lds; single
//    barrier; hot loop barrier-free. Ring-4 float4 guide prefetch.
//  - Nontemporal stores (native vector type): out is never re-read.

namespace {
constexpr int K = 32, C = 32;
constexpr int W = 1024;
constexpr int HW = 1024 * 1024;
constexpr size_t GRDN = (size_t)K * C * 64 * 64;  // floats per image
}

typedef float v4f __attribute__((ext_vector_type(4)));

__device__ __forceinline__ void gl_lds4(const float* src, float* dst) {
    __builtin_amdgcn_global_load_lds(
        (const __attribute__((address_space(1))) void*)src,
        (__attribute__((address_space(3))) void*)dst, 4, 0, 0);
}

__global__ __launch_bounds__(256, 3) void gridup_kernel(
    const float* __restrict__ grd,   // [N][K][C][64][64]
    const float* __restrict__ gm,    // [N][C][1024][1024]
    float* __restrict__ out)         // [N][K][1024][1024]
{
    __shared__ float sM[4][C][K];    // [tile][c][k], 16 KB

    const int b  = blockIdx.x;                 // 0..2047
    const int wq = (b & 7) * 256 + (b >> 3);   // XCD-contiguous quads
    const int t  = threadIdx.x;

    const int g0  = wq * 4;          // quad never crosses a by-row (16 quads/row)
    const int n   = g0 >> 12;
    const int rr  = g0 & 4095;
    const int by  = rr >> 6;
    const int bx0 = rr & 63;         // multiple of 4

    // ---- stage 4 matrices: e = [tl][c][k] linear, 4096 dword gathers
    #pragma unroll
    for (int i = 0; i < 16; ++i) {
        const int e  = i * 256 + t;  // 0..4095
        const int tl = e >> 10;
        const int c  = (e >> 5) & 31;
        const int k  = e & 31;
        gl_lds4(grd + (size_t)n * GRDN + (size_t)(k * 32 + c) * 4096 +
                    by * 64 + bx0 + tl,
                &sM[0][0][0] + e);
    }
    __syncthreads();   // only barrier in the kernel

    const int w = t >> 6;            // wave = tile tl
    const int l = t & 63;
    const int bx = bx0 + w;

    const int row = l >> 2;          // 0..15
    const int col = (l & 3) << 2;    // 0,4,8,12
    const size_t pix = (size_t)(by * 16 + row) * W + bx * 16 + col;
    const float* gb = gm + (size_t)n * C * HW + pix;
    float*       ob = out + (size_t)n * K * HW + pix;
    const float* Mb = &sM[w][0][0];

    // Guide ring, 4 deep, loads land directly in ring slots.
    v4f g[4];
    #pragma unroll
    for (int j = 0; j < 4; ++j)
        g[j] = *reinterpret_cast<const v4f*>(gb + (size_t)j * HW);

    v4f acc[32];
    #pragma unroll
    for (int k = 0; k < 32; ++k) acc[k] = (v4f)0.f;

    #pragma unroll
    for (int c = 0; c < C; ++c) {
        const v4f u = g[c & 3];
        if (c + 4 < C)
            g[c & 3] = *reinterpret_cast<const v4f*>(gb + (size_t)(c + 4) * HW);
        #pragma unroll
        for (int kq = 0; kq < 8; ++kq) {
            // wave-uniform 16B LDS read: broadcast, conflict-free
            const v4f m = *reinterpret_cast<const v4f*>(Mb + c * K + kq * 4);
            acc[kq * 4 + 0] += m.x * u;
            acc[kq * 4 + 1] += m.y * u;
            acc[kq * 4 + 2] += m.z * u;
            acc[kq * 4 + 3] += m.w * u;
        }
    }

    // ---- nontemporal float4 stores: out is never re-read
    #pragma unroll
    for (int k = 0; k < 32; ++k) {
        __builtin_nontemporal_store(acc[k],
            reinterpret_cast<v4f*>(ob + (size_t)k * HW));
    }
}

extern "C" void kernel_launch(void* const* d_in, const int* in_sizes, int n_in,
                              void* d_out, int out_size, void* d_ws, size_t ws_size,
                              hipStream_t stream) {
    const float* grd = (const float*)d_in[0];   // grid:     2*32*32*64*64
    const float* gm  = (const float*)d_in[1];   // guidemap: 2*32*1024*1024
    float* out = (float*)d_out;                 // 2*32*1024*1024 fp32

    gridup_kernel<<<2048, 256, 0, stream>>>(grd, gm, out);
}

// Round 9
// 167.362 us; speedup vs baseline: 5.7453x; 1.6384x over previous
//
#include <hip/hip_runtime.h>

// out[n,k,y,x] = sum_c grid[n,k,c,y/16,x/16] * guidemap[n,c,y,x]
// N=2, K=C=32, H=W=1024, 64x64 tiles of 16x16 px.
//
// R9 = R3 with halved per-byte instruction overhead, UNCONFOUNDED:
//  - Thread = 4 px x 16 k (acc[16] float4 = 64 VGPR, same budget as R3's
//    acc[32][2] -> no spill). WG = 256 thr = 4 waves = 2 adjacent tiles
//    x 2 k-halves; M ds_read_b128 stays wave-uniform broadcast.
//  - Chip-wide wave-uniform LDS reads halve vs R3 (2.1M vs 4.2M instrs);
//    guide-load and store instruction counts also halve (same bytes).
//  - NO nontemporal stores (L2 write-combining must merge the 64B
//    half-lines of adjacent tiles -- R7b proved nt causes ~1.7x WRITE).
//  - Matrices staged once via global_load_lds, single barrier, ring-4
//    float4 guide prefetch, XCD-contiguous tile-pair assignment.

namespace {
constexpr int K = 32, C = 32;
constexpr int W = 1024;
constexpr int HW = 1024 * 1024;
constexpr size_t GRDN = (size_t)K * C * 64 * 64;  // floats per image
}

typedef float v4f __attribute__((ext_vector_type(4)));

__device__ __forceinline__ void gl_lds4(const float* src, float* dst) {
    __builtin_amdgcn_global_load_lds(
        (const __attribute__((address_space(1))) void*)src,
        (__attribute__((address_space(3))) void*)dst, 4, 0, 0);
}

__global__ __launch_bounds__(256, 4) void gridup_kernel(
    const float* __restrict__ grd,   // [N][K][C][64][64]
    const float* __restrict__ gm,    // [N][C][1024][1024]
    float* __restrict__ out)         // [N][K][1024][1024]
{
    __shared__ float sM[2][C][K];    // [tile][c][k], 8 KB

    const int b  = blockIdx.x;                 // 0..4095
    const int wp = (b & 7) * 512 + (b >> 3);   // XCD-contiguous tile pairs
    const int t  = threadIdx.x;

    const int g0  = wp * 2;          // pair shares n, by
    const int n   = g0 >> 12;
    const int rr  = g0 & 4095;
    const int by  = rr >> 6;
    const int bx0 = rr & 63;         // even

    // ---- stage 2 matrices: e = [tl][c][k] linear, 2048 dword gathers
    #pragma unroll
    for (int i = 0; i < 8; ++i) {
        const int e  = i * 256 + t;  // 0..2047
        const int tl = e >> 10;
        const int c  = (e >> 5) & 31;
        const int k  = e & 31;
        gl_lds4(grd + (size_t)n * GRDN + (size_t)(k * 32 + c) * 4096 +
                    by * 64 + bx0 + tl,
                &sM[0][0][0] + e);
    }
    __syncthreads();   // only barrier in the kernel

    const int w  = t >> 6;           // wave 0..3
    const int tl = w >> 1;           // tile of the pair
    const int kh = w & 1;            // k half: 0 -> k 0..15, 1 -> k 16..31
    const int l  = t & 63;
    const int bx = bx0 + tl;

    const int row = l >> 2;          // 0..15
    const int col = (l & 3) << 2;    // 0,4,8,12
    const size_t pix = (size_t)(by * 16 + row) * W + bx * 16 + col;
    const float* gb = gm + (size_t)n * C * HW + pix;
    float*       ob = out + ((size_t)n * K + kh * 16) * HW + pix;
    const float* Mb = &sM[tl][0][kh * 16];

    // Guide ring, 4 deep.
    v4f g[4];
    #pragma unroll
    for (int j = 0; j < 4; ++j)
        g[j] = *reinterpret_cast<const v4f*>(gb + (size_t)j * HW);

    v4f acc[16];
    #pragma unroll
    for (int k = 0; k < 16; ++k) acc[k] = (v4f)0.f;

    #pragma unroll
    for (int c = 0; c < C; ++c) {
        const v4f u = g[c & 3];
        if (c + 4 < C)
            g[c & 3] = *reinterpret_cast<const v4f*>(gb + (size_t)(c + 4) * HW);
        #pragma unroll
        for (int kq = 0; kq < 4; ++kq) {
            // wave-uniform 16B LDS read: broadcast, conflict-free
            const v4f m = *reinterpret_cast<const v4f*>(Mb + c * K + kq * 4);
            acc[kq * 4 + 0] += m.x * u;
            acc[kq * 4 + 1] += m.y * u;
            acc[kq * 4 + 2] += m.z * u;
            acc[kq * 4 + 3] += m.w * u;
        }
    }

    // ---- plain float4 stores: L2 merges adjacent tiles' 64B halves
    #pragma unroll
    for (int k = 0; k < 16; ++k) {
        *reinterpret_cast<v4f*>(ob + (size_t)k * HW) = acc[k];
    }
}

extern "C" void kernel_launch(void* const* d_in, const int* in_sizes, int n_in,
                              void* d_out, int out_size, void* d_ws, size_t ws_size,
                              hipStream_t stream) {
    const float* grd = (const float*)d_in[0];   // grid:     2*32*32*64*64
    const float* gm  = (const float*)d_in[1];   // guidemap: 2*32*1024*1024
    float* out = (float*)d_out;                 // 2*32*1024*1024 fp32

    gridup_kernel<<<4096, 256, 0, stream>>>(grd, gm, out);
}